// Round 1
// baseline (938.446 us; speedup 1.0000x reference)
//
#include <hip/hip_runtime.h>

// Problem constants (from reference setup_inputs)
#define Bb 2
#define Nn 1024
#define Ee 8192
#define DV 64   // IN_V == OUT_V == IN_E == 64

typedef __attribute__((ext_vector_type(8))) short short8;
typedef __attribute__((ext_vector_type(4))) float floatx4;

// fp32 -> bf16 bits, round-to-nearest-even
static __device__ __forceinline__ unsigned short f2bf(float f) {
    unsigned int u = __float_as_uint(f);
    unsigned int r = (u + 0x7FFFu + ((u >> 16) & 1u)) >> 16;
    return (unsigned short)r;
}

// scale[b*E + e] = dot(H_e[row,:64], p[:64]); one wave per row
__global__ __launch_bounds__(256) void scale_kernel(const float* __restrict__ He,
                                                    const float* __restrict__ p,
                                                    float* __restrict__ scale) {
    int wave = threadIdx.x >> 6;
    int lane = threadIdx.x & 63;
    int row = blockIdx.x * 4 + wave;
    float v = He[row * 64 + lane] * p[lane];
    #pragma unroll
    for (int off = 32; off > 0; off >>= 1) v += __shfl_xor(v, off);
    if (lane == 0) scale[row] = v;
}

// HW = H_v @ weight   [B*N,64] @ [64,64]
__global__ __launch_bounds__(256) void hw_kernel(const float* __restrict__ Hv,
                                                 const float* __restrict__ W,
                                                 float* __restrict__ HWo) {
    __shared__ float Ws[64 * 64];
    __shared__ float Hvs[4 * 64];
    int t = threadIdx.x;
    for (int i = t; i < 4096; i += 256) Ws[i] = W[i];
    int r0 = blockIdx.x * 4;
    Hvs[t] = Hv[(size_t)r0 * 64 + t];
    __syncthreads();
    int d = t & 63, rr = t >> 6;
    float acc = 0.f;
    #pragma unroll
    for (int c = 0; c < 64; ++c) acc += Hvs[rr * 64 + c] * Ws[c * 64 + d];
    HWo[(size_t)(r0 + rr) * 64 + d] = acc;
}

// adjusted_A[b,n,m] = ((n==m) ? 1 : sum_e T[n,e]*scale[e]*T[m,e]) * adj_v[b,n,m]
// 64x64 tile per block, 4 waves, bf16 MFMA 16x16x32, K-chunk 64
__global__ __launch_bounds__(256) void mm_kernel(const float* __restrict__ T,
                                                 const float* __restrict__ scale,
                                                 const float* __restrict__ adj_v,
                                                 float* __restrict__ Aout) {
    __shared__ __attribute__((aligned(16))) unsigned short As[64 * 72];
    __shared__ __attribute__((aligned(16))) unsigned short Bs[64 * 72];
    const int t = threadIdx.x;
    const int b = blockIdx.z;
    const int n0 = blockIdx.y * 64;
    const int m0 = blockIdx.x * 64;
    const int lane = t & 63;
    const int w = t >> 6;
    const int quad = lane >> 4;
    const int l15 = lane & 15;

    const int srow = t >> 4;    // 0..15 staging row group
    const int scol4 = t & 15;   // float4 column

    const float* Tb = T + (size_t)b * Nn * Ee;
    const float* sc = scale + (size_t)b * Ee;

    floatx4 acc[4];
    #pragma unroll
    for (int j = 0; j < 4; ++j) acc[j] = (floatx4){0.f, 0.f, 0.f, 0.f};

    for (int k0 = 0; k0 < Ee; k0 += 64) {
        floatx4 s4 = *(const floatx4*)&sc[k0 + scol4 * 4];
        #pragma unroll
        for (int rr = 0; rr < 4; ++rr) {
            int row = srow + rr * 16;
            floatx4 a  = *(const floatx4*)&Tb[(size_t)(n0 + row) * Ee + k0 + scol4 * 4];
            floatx4 bv = *(const floatx4*)&Tb[(size_t)(m0 + row) * Ee + k0 + scol4 * 4];
            ushort4 abf, bbf;
            abf.x = f2bf(a.x * s4.x); abf.y = f2bf(a.y * s4.y);
            abf.z = f2bf(a.z * s4.z); abf.w = f2bf(a.w * s4.w);
            bbf.x = f2bf(bv.x); bbf.y = f2bf(bv.y);
            bbf.z = f2bf(bv.z); bbf.w = f2bf(bv.w);
            *(ushort4*)&As[row * 72 + scol4 * 4] = abf;
            *(ushort4*)&Bs[row * 72 + scol4 * 4] = bbf;
        }
        __syncthreads();
        #pragma unroll
        for (int kk = 0; kk < 64; kk += 32) {
            short8 af = *(const short8*)&As[(w * 16 + l15) * 72 + kk + quad * 8];
            #pragma unroll
            for (int j = 0; j < 4; ++j) {
                short8 bf = *(const short8*)&Bs[(j * 16 + l15) * 72 + kk + quad * 8];
                acc[j] = __builtin_amdgcn_mfma_f32_16x16x32_bf16(af, bf, acc[j], 0, 0, 0);
            }
        }
        __syncthreads();
    }

    // C/D layout: row = quad*4 + i (n), col = lane&15 (m)  [measured m89/m91]
    #pragma unroll
    for (int j = 0; j < 4; ++j) {
        #pragma unroll
        for (int i = 0; i < 4; ++i) {
            int gn = n0 + w * 16 + quad * 4 + i;
            int gm = m0 + j * 16 + l15;
            float v = acc[j][i];
            if (gn == gm) v = 1.0f;
            size_t idx = ((size_t)b * Nn + gn) * Nn + gm;
            Aout[idx] = v * adj_v[idx];
        }
    }
}

// out[b,n,d] = sum_m adjusted_A[b,n,m] * HW[b,m,d] + bias[d]
__global__ __launch_bounds__(256) void out_kernel(const float* __restrict__ A,
                                                  const float* __restrict__ HWo,
                                                  const float* __restrict__ bias,
                                                  float* __restrict__ out) {
    __shared__ float HWs[64 * 64];
    __shared__ float Ash[8 * 64];
    int t = threadIdx.x;
    int b = blockIdx.y;
    int n0 = blockIdx.x * 8;
    int d = t & 63;
    int rr = t >> 6;  // 0..3, handles rows rr and rr+4
    float acc0 = 0.f, acc1 = 0.f;
    for (int m0 = 0; m0 < Nn; m0 += 64) {
        for (int i = t; i < 4096; i += 256) {
            int r = i >> 6, c = i & 63;
            HWs[i] = HWo[((size_t)b * Nn + m0 + r) * 64 + c];
        }
        {
            int i = t;  // 512 elements, 256 threads -> 2 each
            int r = i >> 6, c = i & 63;
            Ash[i] = A[((size_t)b * Nn + n0 + r) * Nn + m0 + c];
            i += 256; r = i >> 6; c = i & 63;
            Ash[i] = A[((size_t)b * Nn + n0 + r) * Nn + m0 + c];
        }
        __syncthreads();
        #pragma unroll
        for (int mm = 0; mm < 64; ++mm) {
            float hw = HWs[mm * 64 + d];
            acc0 += Ash[rr * 64 + mm] * hw;
            acc1 += Ash[(rr + 4) * 64 + mm] * hw;
        }
        __syncthreads();
    }
    float bd = bias[d];
    out[((size_t)b * Nn + n0 + rr) * 64 + d] = acc0 + bd;
    out[((size_t)b * Nn + n0 + rr + 4) * 64 + d] = acc1 + bd;
}

extern "C" void kernel_launch(void* const* d_in, const int* in_sizes, int n_in,
                              void* d_out, int out_size, void* d_ws, size_t ws_size,
                              hipStream_t stream) {
    const float* H_v    = (const float*)d_in[0];
    const float* H_e    = (const float*)d_in[1];
    // d_in[2] = adj_e : UNUSED by the reference output
    const float* adj_v  = (const float*)d_in[3];
    const float* T      = (const float*)d_in[4];
    const float* weight = (const float*)d_in[5];
    const float* p      = (const float*)d_in[6];
    const float* bias   = (const float*)d_in[7];
    float* out = (float*)d_out;

    char* ws = (char*)d_ws;
    float* scale = (float*)ws;                           // 16384 floats  (64 KB)
    float* HWo   = (float*)(ws + 65536);                 // 131072 floats (512 KB)
    float* Aout  = (float*)(ws + 65536 + 524288);        // 2M floats     (8 MB)

    // Output chunk 1: H_e passthrough (fp32, exact)
    hipMemcpyAsync(out + (size_t)Bb * Nn * DV, H_e,
                   (size_t)Bb * Ee * 64 * sizeof(float),
                   hipMemcpyDeviceToDevice, stream);

    scale_kernel<<<dim3(Bb * Ee / 4), dim3(256), 0, stream>>>(H_e, p, scale);
    hw_kernel<<<dim3(Bb * Nn / 4), dim3(256), 0, stream>>>(H_v, weight, HWo);
    mm_kernel<<<dim3(Nn / 64, Nn / 64, Bb), dim3(256), 0, stream>>>(T, scale, adj_v, Aout);
    out_kernel<<<dim3(Nn / 8, Bb), dim3(256), 0, stream>>>(Aout, HWo, bias, out);
}

// Round 2
// 726.498 us; speedup vs baseline: 1.2917x; 1.2917x over previous
//
#include <hip/hip_runtime.h>

// Problem constants (from reference setup_inputs)
#define Bb 2
#define Nn 1024
#define Ee 8192
#define DV 64   // IN_V == OUT_V == IN_E == 64

typedef __attribute__((ext_vector_type(8))) short short8;
typedef __attribute__((ext_vector_type(4))) float floatx4;

// fp32 -> bf16 bits, round-to-nearest-even
static __device__ __forceinline__ unsigned short f2bf(float f) {
    unsigned int u = __float_as_uint(f);
    unsigned int r = (u + 0x7FFFu + ((u >> 16) & 1u)) >> 16;
    return (unsigned short)r;
}

// scale[b*E + e] = dot(H_e[row,:64], p[:64]); one wave per row
__global__ __launch_bounds__(256) void scale_kernel(const float* __restrict__ He,
                                                    const float* __restrict__ p,
                                                    float* __restrict__ scale) {
    int wave = threadIdx.x >> 6;
    int lane = threadIdx.x & 63;
    int row = blockIdx.x * 4 + wave;
    float v = He[row * 64 + lane] * p[lane];
    #pragma unroll
    for (int off = 32; off > 0; off >>= 1) v += __shfl_xor(v, off);
    if (lane == 0) scale[row] = v;
}

// Pre-cast T (fp32) -> Tsc (bf16, scaled by scale[e]) and Tpl (bf16, plain)
__global__ __launch_bounds__(256) void cast_kernel(const float* __restrict__ T,
                                                   const float* __restrict__ scale,
                                                   unsigned short* __restrict__ Tsc,
                                                   unsigned short* __restrict__ Tpl) {
    size_t i4 = (size_t)blockIdx.x * 256 + threadIdx.x;   // float4 index
    size_t e0 = i4 * 4;                                   // element index
    int b = (int)(e0 >> 23);                              // 2^23 elems per batch
    int e = (int)(e0 & 8191);                             // column within row
    floatx4 t = *(const floatx4*)&T[e0];
    floatx4 s = *(const floatx4*)&scale[(size_t)b * Ee + e];
    ushort4 sc, pl;
    sc.x = f2bf(t.x * s.x); sc.y = f2bf(t.y * s.y);
    sc.z = f2bf(t.z * s.z); sc.w = f2bf(t.w * s.w);
    pl.x = f2bf(t.x); pl.y = f2bf(t.y);
    pl.z = f2bf(t.z); pl.w = f2bf(t.w);
    *(ushort4*)&Tsc[e0] = sc;
    *(ushort4*)&Tpl[e0] = pl;
}

// HW = H_v @ weight   [B*N,64] @ [64,64]
__global__ __launch_bounds__(256) void hw_kernel(const float* __restrict__ Hv,
                                                 const float* __restrict__ W,
                                                 float* __restrict__ HWo) {
    __shared__ float Ws[64 * 64];
    __shared__ float Hvs[4 * 64];
    int t = threadIdx.x;
    for (int i = t; i < 4096; i += 256) Ws[i] = W[i];
    int r0 = blockIdx.x * 4;
    Hvs[t] = Hv[(size_t)r0 * 64 + t];
    __syncthreads();
    int d = t & 63, rr = t >> 6;
    float acc = 0.f;
    #pragma unroll
    for (int c = 0; c < 64; ++c) acc += Hvs[rr * 64 + c] * Ws[c * 64 + d];
    HWo[(size_t)(r0 + rr) * 64 + d] = acc;
}

// Partial M1 tiles: upper-triangular 128x128 tiles, K-split 7.
// Ppart[(b*36+tile)*7 + s][128*128] = sum over K-chunk s of Tsc[n,:]·Tpl[m,:]
__global__ __launch_bounds__(256, 2) void mm_kernel(const unsigned short* __restrict__ Tsc,
                                                    const unsigned short* __restrict__ Tpl,
                                                    float* __restrict__ Ppart) {
    __shared__ __attribute__((aligned(16))) unsigned short As[128 * 72];
    __shared__ __attribute__((aligned(16))) unsigned short Bs[128 * 72];
    const int t = threadIdx.x;
    const int tile = blockIdx.x;     // 0..35 upper-triangular
    const int b = blockIdx.y;
    const int s = blockIdx.z;        // 0..6 K-split

    // decode triangular tile -> (i,j), i<=j, 8x8 grid
    int i = 0, rem = tile;
    while (rem >= 8 - i) { rem -= 8 - i; ++i; }
    const int j = i + rem;
    const int n0 = i * 128, m0 = j * 128;

    const unsigned short* Arow = Tsc + ((size_t)b * Nn + n0) * Ee;
    const unsigned short* Brow = Tpl + ((size_t)b * Nn + m0) * Ee;

    // K range for this split (units of 64-elem chunks; 128 chunks total over 7 splits)
    const int kc0 = (s * 128) / 7 * 64;
    const int kc1 = ((s + 1) * 128) / 7 * 64;

    const int lane = t & 63;
    const int w = t >> 6;
    const int wr = w >> 1, wc = w & 1;      // 2x2 wave grid, each wave 64x64
    const int quad = lane >> 4;
    const int l15 = lane & 15;

    // staging: slot = t + u*256; r = slot>>3 (0..127), c8 = slot&7 (16B col group)
    const int r0s = t >> 3;
    const int c8 = t & 7;

    floatx4 acc[4][4];
    #pragma unroll
    for (int a = 0; a < 4; ++a)
        #pragma unroll
        for (int c = 0; c < 4; ++c) acc[a][c] = (floatx4){0.f, 0.f, 0.f, 0.f};

    for (int k0 = kc0; k0 < kc1; k0 += 64) {
        #pragma unroll
        for (int u = 0; u < 4; ++u) {
            int r = r0s + u * 32;
            short8 av = *(const short8*)&Arow[(size_t)r * Ee + k0 + c8 * 8];
            short8 bv = *(const short8*)&Brow[(size_t)r * Ee + k0 + c8 * 8];
            *(short8*)&As[r * 72 + c8 * 8] = av;
            *(short8*)&Bs[r * 72 + c8 * 8] = bv;
        }
        __syncthreads();
        #pragma unroll
        for (int kk = 0; kk < 64; kk += 32) {
            short8 af[4], bf[4];
            #pragma unroll
            for (int a = 0; a < 4; ++a)
                af[a] = *(const short8*)&As[(wr * 64 + a * 16 + l15) * 72 + kk + quad * 8];
            #pragma unroll
            for (int c = 0; c < 4; ++c)
                bf[c] = *(const short8*)&Bs[(wc * 64 + c * 16 + l15) * 72 + kk + quad * 8];
            #pragma unroll
            for (int a = 0; a < 4; ++a)
                #pragma unroll
                for (int c = 0; c < 4; ++c)
                    acc[a][c] = __builtin_amdgcn_mfma_f32_16x16x32_bf16(af[a], bf[c], acc[a][c], 0, 0, 0);
        }
        __syncthreads();
    }

    float* P = Ppart + (((size_t)(b * 36 + tile)) * 7 + s) * 16384;
    #pragma unroll
    for (int a = 0; a < 4; ++a)
        #pragma unroll
        for (int c = 0; c < 4; ++c)
            #pragma unroll
            for (int v = 0; v < 4; ++v) {
                int r = wr * 64 + a * 16 + quad * 4 + v;
                int cc = wc * 64 + c * 16 + l15;
                P[r * 128 + cc] = acc[a][c][v];
            }
}

// Sum K-split partials, diag override, Hadamard with adj_v, write both orientations.
__global__ __launch_bounds__(256) void reduce_kernel(const float* __restrict__ Ppart,
                                                     const float* __restrict__ adj_v,
                                                     float* __restrict__ Aout) {
    __shared__ float Ls[64 * 133];
    const int t = threadIdx.x;
    const int job = blockIdx.x;        // 0..71
    const int b = job / 36;
    const int tile = job % 36;
    int i = 0, rem = tile;
    while (rem >= 8 - i) { rem -= 8 - i; ++i; }
    const int j = i + rem;
    const int n0 = i * 128, m0 = j * 128;
    const float* P = Ppart + (size_t)job * 7 * 16384;
    const float* AV = adj_v + (size_t)b * Nn * Nn;
    float* AO = Aout + (size_t)b * Nn * Nn;

    for (int h = 0; h < 2; ++h) {
        // sum partials for 64 rows x 128 cols; write normal orientation
        #pragma unroll
        for (int it = 0; it < 8; ++it) {
            int f = it * 256 + t;          // float4 id over 64x128
            int r = f >> 5;                // 32 float4 per row
            int c = (f & 31) * 4;
            floatx4 v = (floatx4){0.f, 0.f, 0.f, 0.f};
            #pragma unroll
            for (int s = 0; s < 7; ++s) {
                floatx4 pv = *(const floatx4*)&P[s * 16384 + (h * 64 + r) * 128 + c];
                v.x += pv.x; v.y += pv.y; v.z += pv.z; v.w += pv.w;
            }
            int gn = n0 + h * 64 + r;
            int gm = m0 + c;
            if (i == j) {
                if (gn == gm) v.x = 1.f;
                if (gn == gm + 1) v.y = 1.f;
                if (gn == gm + 2) v.z = 1.f;
                if (gn == gm + 3) v.w = 1.f;
            }
            Ls[r * 133 + c] = v.x; Ls[r * 133 + c + 1] = v.y;
            Ls[r * 133 + c + 2] = v.z; Ls[r * 133 + c + 3] = v.w;
            floatx4 a = *(const floatx4*)&AV[(size_t)gn * Nn + gm];
            floatx4 o = (floatx4){v.x * a.x, v.y * a.y, v.z * a.z, v.w * a.w};
            *(floatx4*)&AO[(size_t)gn * Nn + gm] = o;
        }
        __syncthreads();
        if (i != j) {
            // transposed block: rows m0..m0+127, cols n0+h*64..+63
            #pragma unroll
            for (int it = 0; it < 8; ++it) {
                int f = it * 256 + t;      // float4 over 128 x 16
                int m = f >> 4;
                int cn = (f & 15) * 4;     // n_local
                floatx4 v;
                v.x = Ls[(cn + 0) * 133 + m];
                v.y = Ls[(cn + 1) * 133 + m];
                v.z = Ls[(cn + 2) * 133 + m];
                v.w = Ls[(cn + 3) * 133 + m];
                int grow = m0 + m;
                int gcol = n0 + h * 64 + cn;
                floatx4 a = *(const floatx4*)&AV[(size_t)grow * Nn + gcol];
                floatx4 o = (floatx4){v.x * a.x, v.y * a.y, v.z * a.z, v.w * a.w};
                *(floatx4*)&AO[(size_t)grow * Nn + gcol] = o;
            }
        }
        __syncthreads();
    }
}

// out[b,n,d] = sum_m adjusted_A[b,n,m] * HW[b,m,d] + bias[d]
__global__ __launch_bounds__(256) void out_kernel(const float* __restrict__ A,
                                                  const float* __restrict__ HWo,
                                                  const float* __restrict__ bias,
                                                  float* __restrict__ out) {
    __shared__ float HWs[64 * 64];
    __shared__ float Ash[8 * 64];
    int t = threadIdx.x;
    int b = blockIdx.y;
    int n0 = blockIdx.x * 8;
    int d = t & 63;
    int rr = t >> 6;  // 0..3, handles rows rr and rr+4
    float acc0 = 0.f, acc1 = 0.f;
    for (int m0 = 0; m0 < Nn; m0 += 64) {
        for (int i = t; i < 4096; i += 256) {
            int r = i >> 6, c = i & 63;
            HWs[i] = HWo[((size_t)b * Nn + m0 + r) * 64 + c];
        }
        {
            int i = t;
            int r = i >> 6, c = i & 63;
            Ash[i] = A[((size_t)b * Nn + n0 + r) * Nn + m0 + c];
            i += 256; r = i >> 6; c = i & 63;
            Ash[i] = A[((size_t)b * Nn + n0 + r) * Nn + m0 + c];
        }
        __syncthreads();
        #pragma unroll
        for (int mm = 0; mm < 64; ++mm) {
            float hw = HWs[mm * 64 + d];
            acc0 += Ash[rr * 64 + mm] * hw;
            acc1 += Ash[(rr + 4) * 64 + mm] * hw;
        }
        __syncthreads();
    }
    float bd = bias[d];
    out[((size_t)b * Nn + n0 + rr) * 64 + d] = acc0 + bd;
    out[((size_t)b * Nn + n0 + rr + 4) * 64 + d] = acc1 + bd;
}

extern "C" void kernel_launch(void* const* d_in, const int* in_sizes, int n_in,
                              void* d_out, int out_size, void* d_ws, size_t ws_size,
                              hipStream_t stream) {
    const float* H_v    = (const float*)d_in[0];
    const float* H_e    = (const float*)d_in[1];
    // d_in[2] = adj_e : UNUSED by the reference output
    const float* adj_v  = (const float*)d_in[3];
    const float* T      = (const float*)d_in[4];
    const float* weight = (const float*)d_in[5];
    const float* p      = (const float*)d_in[6];
    const float* bias   = (const float*)d_in[7];
    float* out = (float*)d_out;

    char* ws = (char*)d_ws;
    float* scale          = (float*)ws;                        // 64 KB
    float* HWo            = (float*)(ws + (1 << 16));          // 512 KB
    unsigned short* Tsc   = (unsigned short*)(ws + (1 << 20));             // 32 MB
    unsigned short* Tpl   = (unsigned short*)(ws + (1 << 20) + (32u << 20)); // 32 MB
    float* Ppart          = (float*)(ws + (1 << 20) + (64u << 20));        // 33 MB (504*16384*4)
    float* Aout           = (float*)(ws + (1 << 20) + (98u << 20));        // 8 MB

    // Output chunk 1: H_e passthrough (fp32, exact)
    hipMemcpyAsync(out + (size_t)Bb * Nn * DV, H_e,
                   (size_t)Bb * Ee * 64 * sizeof(float),
                   hipMemcpyDeviceToDevice, stream);

    scale_kernel<<<dim3(Bb * Ee / 4), dim3(256), 0, stream>>>(H_e, p, scale);
    cast_kernel<<<dim3((Bb * Nn * Ee / 4) / 256), dim3(256), 0, stream>>>(T, scale, Tsc, Tpl);
    hw_kernel<<<dim3(Bb * Nn / 4), dim3(256), 0, stream>>>(H_v, weight, HWo);
    mm_kernel<<<dim3(36, Bb, 7), dim3(256), 0, stream>>>(Tsc, Tpl, Ppart);
    reduce_kernel<<<dim3(36 * Bb), dim3(256), 0, stream>>>(Ppart, adj_v, Aout);
    out_kernel<<<dim3(Nn / 8, Bb), dim3(256), 0, stream>>>(Aout, HWo, bias, out);
}

// Round 3
// 714.107 us; speedup vs baseline: 1.3142x; 1.0174x over previous
//
#include <hip/hip_runtime.h>

// Problem constants (from reference setup_inputs)
#define Bb 2
#define Nn 1024
#define Ee 8192
#define DV 64   // IN_V == OUT_V == IN_E == 64

typedef __attribute__((ext_vector_type(8))) short short8;
typedef __attribute__((ext_vector_type(4))) float floatx4;

// fp32 -> bf16 bits, round-to-nearest-even
static __device__ __forceinline__ unsigned short f2bf(float f) {
    unsigned int u = __float_as_uint(f);
    unsigned int r = (u + 0x7FFFu + ((u >> 16) & 1u)) >> 16;
    return (unsigned short)r;
}

// scale[b*E + e] = dot(H_e[row,:64], p[:64]); one wave per row
__global__ __launch_bounds__(256) void scale_kernel(const float* __restrict__ He,
                                                    const float* __restrict__ p,
                                                    float* __restrict__ scale) {
    int wave = threadIdx.x >> 6;
    int lane = threadIdx.x & 63;
    int row = blockIdx.x * 4 + wave;
    float v = He[row * 64 + lane] * p[lane];
    #pragma unroll
    for (int off = 32; off > 0; off >>= 1) v += __shfl_xor(v, off);
    if (lane == 0) scale[row] = v;
}

// Pre-cast T (fp32) -> Tsc (bf16, scaled by scale[e]) and Tpl (bf16, plain)
__global__ __launch_bounds__(256) void cast_kernel(const float* __restrict__ T,
                                                   const float* __restrict__ scale,
                                                   unsigned short* __restrict__ Tsc,
                                                   unsigned short* __restrict__ Tpl) {
    size_t i4 = (size_t)blockIdx.x * 256 + threadIdx.x;   // float4 index
    size_t e0 = i4 * 4;                                   // element index
    int b = (int)(e0 >> 23);                              // 2^23 elems per batch
    int e = (int)(e0 & 8191);                             // column within row
    floatx4 t = *(const floatx4*)&T[e0];
    floatx4 s = *(const floatx4*)&scale[(size_t)b * Ee + e];
    ushort4 sc, pl;
    sc.x = f2bf(t.x * s.x); sc.y = f2bf(t.y * s.y);
    sc.z = f2bf(t.z * s.z); sc.w = f2bf(t.w * s.w);
    pl.x = f2bf(t.x); pl.y = f2bf(t.y);
    pl.z = f2bf(t.z); pl.w = f2bf(t.w);
    *(ushort4*)&Tsc[e0] = sc;
    *(ushort4*)&Tpl[e0] = pl;
}

// HW = H_v @ weight   [B*N,64] @ [64,64]
__global__ __launch_bounds__(256) void hw_kernel(const float* __restrict__ Hv,
                                                 const float* __restrict__ W,
                                                 float* __restrict__ HWo) {
    __shared__ float Ws[64 * 64];
    __shared__ float Hvs[4 * 64];
    int t = threadIdx.x;
    for (int i = t; i < 4096; i += 256) Ws[i] = W[i];
    int r0 = blockIdx.x * 4;
    Hvs[t] = Hv[(size_t)r0 * 64 + t];
    __syncthreads();
    int d = t & 63, rr = t >> 6;
    float acc = 0.f;
    #pragma unroll
    for (int c = 0; c < 64; ++c) acc += Hvs[rr * 64 + c] * Ws[c * 64 + d];
    HWo[(size_t)(r0 + rr) * 64 + d] = acc;
}

// Partial M1 tiles: upper-triangular 128x128 tiles, K-split 7.
// global_load_lds (16B) staging into XOR-swizzled LDS:
//   LDS slot (row, c8) holds global 8-short chunk (c8 ^ (row&7)) of that row.
// Staging lane l (per wave, per 8-row group): row = base + (l>>3), slot c8 = l&7,
//   so it must FETCH global chunk (l&7) ^ (l>>3)  -- loop-invariant per lane.
// MFMA ds_read for chunk c of row r reads slot c ^ (r&7): each 4-bank group
// gets exactly 8 lanes of the b128 -> balanced, conflict-free.
__global__ __launch_bounds__(256, 2) void mm_kernel(const unsigned short* __restrict__ Tsc,
                                                    const unsigned short* __restrict__ Tpl,
                                                    float* __restrict__ Ppart) {
    __shared__ __attribute__((aligned(16))) unsigned short As[128 * 64];
    __shared__ __attribute__((aligned(16))) unsigned short Bs[128 * 64];
    const int t = threadIdx.x;
    const int tile = blockIdx.x;     // 0..35 upper-triangular
    const int b = blockIdx.y;
    const int s = blockIdx.z;        // 0..6 K-split

    // decode triangular tile -> (i,j), i<=j, 8x8 grid
    int i = 0, rem = tile;
    while (rem >= 8 - i) { rem -= 8 - i; ++i; }
    const int j = i + rem;
    const int n0 = i * 128, m0 = j * 128;

    const int lane = t & 63;
    const int w = t >> 6;
    const int wr = w >> 1, wc = w & 1;      // 2x2 wave grid, each wave 64x64
    const int quad = lane >> 4;
    const int l15 = lane & 15;
    const int l7 = l15 & 7;

    const int lr = lane >> 3;               // 0..7: row within staged 8-row group
    const int lc = (lane & 7) ^ lr;         // swizzled global chunk this lane fetches

    // K range (units of 64-elem chunks; 128 chunks over 7 splits)
    const int kc0 = (s * 128) / 7 * 64;
    const int kc1 = ((s + 1) * 128) / 7 * 64;

    // per-lane global source pointers (advance by 64 shorts per K-iter)
    const unsigned short* gA = Tsc + ((size_t)b * Nn + n0 + w * 32 + lr) * Ee + kc0 + lc * 8;
    const unsigned short* gB = Tpl + ((size_t)b * Nn + m0 + w * 32 + lr) * Ee + kc0 + lc * 8;
    // per-lane LDS dest (wave-uniform base + lane*16B)
    unsigned short* lA = As + (w * 32) * 64 + lane * 8;
    unsigned short* lB = Bs + (w * 32) * 64 + lane * 8;

    floatx4 acc[4][4];
    #pragma unroll
    for (int a = 0; a < 4; ++a)
        #pragma unroll
        for (int c = 0; c < 4; ++c) acc[a][c] = (floatx4){0.f, 0.f, 0.f, 0.f};

    for (int k0 = kc0; k0 < kc1; k0 += 64) {
        #pragma unroll
        for (int u = 0; u < 4; ++u) {
            __builtin_amdgcn_global_load_lds(
                (const __attribute__((address_space(1))) unsigned int*)(gA + (size_t)u * 8 * Ee),
                (__attribute__((address_space(3))) unsigned int*)(lA + u * 8 * 64), 16, 0, 0);
            __builtin_amdgcn_global_load_lds(
                (const __attribute__((address_space(1))) unsigned int*)(gB + (size_t)u * 8 * Ee),
                (__attribute__((address_space(3))) unsigned int*)(lB + u * 8 * 64), 16, 0, 0);
        }
        gA += 64; gB += 64;
        __syncthreads();
        #pragma unroll
        for (int kk8 = 0; kk8 < 8; kk8 += 4) {
            short8 af[4], bf[4];
            #pragma unroll
            for (int a = 0; a < 4; ++a)
                af[a] = *(const short8*)&As[(wr * 64 + a * 16 + l15) * 64 + ((kk8 + quad) ^ l7) * 8];
            #pragma unroll
            for (int c = 0; c < 4; ++c)
                bf[c] = *(const short8*)&Bs[(wc * 64 + c * 16 + l15) * 64 + ((kk8 + quad) ^ l7) * 8];
            #pragma unroll
            for (int a = 0; a < 4; ++a)
                #pragma unroll
                for (int c = 0; c < 4; ++c)
                    acc[a][c] = __builtin_amdgcn_mfma_f32_16x16x32_bf16(af[a], bf[c], acc[a][c], 0, 0, 0);
        }
        __syncthreads();
    }

    float* P = Ppart + (((size_t)(b * 36 + tile)) * 7 + s) * 16384;
    #pragma unroll
    for (int a = 0; a < 4; ++a)
        #pragma unroll
        for (int c = 0; c < 4; ++c)
            #pragma unroll
            for (int v = 0; v < 4; ++v) {
                int r = wr * 64 + a * 16 + quad * 4 + v;
                int cc = wc * 64 + c * 16 + l15;
                P[r * 128 + cc] = acc[a][c][v];
            }
}

// Sum K-split partials, diag override, Hadamard with adj_v, write both orientations.
// Grid: (72 jobs, 2 halves) -> 144 blocks.
__global__ __launch_bounds__(256) void reduce_kernel(const float* __restrict__ Ppart,
                                                     const float* __restrict__ adj_v,
                                                     float* __restrict__ Aout) {
    __shared__ float Ls[64 * 133];
    const int t = threadIdx.x;
    const int job = blockIdx.x;        // 0..71
    const int h = blockIdx.y;          // 0..1
    const int b = job / 36;
    const int tile = job % 36;
    int i = 0, rem = tile;
    while (rem >= 8 - i) { rem -= 8 - i; ++i; }
    const int j = i + rem;
    const int n0 = i * 128, m0 = j * 128;
    const float* P = Ppart + (size_t)job * 7 * 16384;
    const float* AV = adj_v + (size_t)b * Nn * Nn;
    float* AO = Aout + (size_t)b * Nn * Nn;

    // sum partials for 64 rows x 128 cols; write normal orientation
    #pragma unroll
    for (int it = 0; it < 8; ++it) {
        int f = it * 256 + t;          // float4 id over 64x128
        int r = f >> 5;                // 32 float4 per row
        int c = (f & 31) * 4;
        floatx4 v = (floatx4){0.f, 0.f, 0.f, 0.f};
        #pragma unroll
        for (int s = 0; s < 7; ++s) {
            floatx4 pv = *(const floatx4*)&P[s * 16384 + (h * 64 + r) * 128 + c];
            v.x += pv.x; v.y += pv.y; v.z += pv.z; v.w += pv.w;
        }
        int gn = n0 + h * 64 + r;
        int gm = m0 + c;
        if (i == j) {
            if (gn == gm) v.x = 1.f;
            if (gn == gm + 1) v.y = 1.f;
            if (gn == gm + 2) v.z = 1.f;
            if (gn == gm + 3) v.w = 1.f;
        }
        Ls[r * 133 + c] = v.x; Ls[r * 133 + c + 1] = v.y;
        Ls[r * 133 + c + 2] = v.z; Ls[r * 133 + c + 3] = v.w;
        floatx4 a = *(const floatx4*)&AV[(size_t)gn * Nn + gm];
        floatx4 o = (floatx4){v.x * a.x, v.y * a.y, v.z * a.z, v.w * a.w};
        *(floatx4*)&AO[(size_t)gn * Nn + gm] = o;
    }
    __syncthreads();
    if (i != j) {
        // transposed block: rows m0..m0+127, cols n0+h*64..+63
        #pragma unroll
        for (int it = 0; it < 8; ++it) {
            int f = it * 256 + t;      // float4 over 128 x 16
            int m = f >> 4;
            int cn = (f & 15) * 4;     // n_local
            floatx4 v;
            v.x = Ls[(cn + 0) * 133 + m];
            v.y = Ls[(cn + 1) * 133 + m];
            v.z = Ls[(cn + 2) * 133 + m];
            v.w = Ls[(cn + 3) * 133 + m];
            int grow = m0 + m;
            int gcol = n0 + h * 64 + cn;
            floatx4 a = *(const floatx4*)&AV[(size_t)grow * Nn + gcol];
            floatx4 o = (floatx4){v.x * a.x, v.y * a.y, v.z * a.z, v.w * a.w};
            *(floatx4*)&AO[(size_t)grow * Nn + gcol] = o;
        }
    }
}

// out[b,n,d] = sum_m adjusted_A[b,n,m] * HW[b,m,d] + bias[d]
__global__ __launch_bounds__(256) void out_kernel(const float* __restrict__ A,
                                                  const float* __restrict__ HWo,
                                                  const float* __restrict__ bias,
                                                  float* __restrict__ out) {
    __shared__ float HWs[64 * 64];
    __shared__ float Ash[8 * 64];
    int t = threadIdx.x;
    int b = blockIdx.y;
    int n0 = blockIdx.x * 8;
    int d = t & 63;
    int rr = t >> 6;  // 0..3, handles rows rr and rr+4
    float acc0 = 0.f, acc1 = 0.f;
    for (int m0 = 0; m0 < Nn; m0 += 64) {
        for (int i = t; i < 4096; i += 256) {
            int r = i >> 6, c = i & 63;
            HWs[i] = HWo[((size_t)b * Nn + m0 + r) * 64 + c];
        }
        {
            int i = t;
            int r = i >> 6, c = i & 63;
            Ash[i] = A[((size_t)b * Nn + n0 + r) * Nn + m0 + c];
            i += 256; r = i >> 6; c = i & 63;
            Ash[i] = A[((size_t)b * Nn + n0 + r) * Nn + m0 + c];
        }
        __syncthreads();
        #pragma unroll
        for (int mm = 0; mm < 64; ++mm) {
            float hw = HWs[mm * 64 + d];
            acc0 += Ash[rr * 64 + mm] * hw;
            acc1 += Ash[(rr + 4) * 64 + mm] * hw;
        }
        __syncthreads();
    }
    float bd = bias[d];
    out[((size_t)b * Nn + n0 + rr) * 64 + d] = acc0 + bd;
    out[((size_t)b * Nn + n0 + rr + 4) * 64 + d] = acc1 + bd;
}

extern "C" void kernel_launch(void* const* d_in, const int* in_sizes, int n_in,
                              void* d_out, int out_size, void* d_ws, size_t ws_size,
                              hipStream_t stream) {
    const float* H_v    = (const float*)d_in[0];
    const float* H_e    = (const float*)d_in[1];
    // d_in[2] = adj_e : UNUSED by the reference output
    const float* adj_v  = (const float*)d_in[3];
    const float* T      = (const float*)d_in[4];
    const float* weight = (const float*)d_in[5];
    const float* p      = (const float*)d_in[6];
    const float* bias   = (const float*)d_in[7];
    float* out = (float*)d_out;

    char* ws = (char*)d_ws;
    float* scale          = (float*)ws;                        // 64 KB
    float* HWo            = (float*)(ws + (1 << 16));          // 512 KB
    unsigned short* Tsc   = (unsigned short*)(ws + (1 << 20));               // 32 MB
    unsigned short* Tpl   = (unsigned short*)(ws + (1 << 20) + (32u << 20)); // 32 MB
    float* Ppart          = (float*)(ws + (1 << 20) + (64u << 20));          // 33 MB
    float* Aout           = (float*)(ws + (1 << 20) + (98u << 20));          // 8 MB

    // Output chunk 1: H_e passthrough (fp32, exact)
    hipMemcpyAsync(out + (size_t)Bb * Nn * DV, H_e,
                   (size_t)Bb * Ee * 64 * sizeof(float),
                   hipMemcpyDeviceToDevice, stream);

    scale_kernel<<<dim3(Bb * Ee / 4), dim3(256), 0, stream>>>(H_e, p, scale);
    cast_kernel<<<dim3((Bb * Nn * Ee / 4) / 256), dim3(256), 0, stream>>>(T, scale, Tsc, Tpl);
    hw_kernel<<<dim3(Bb * Nn / 4), dim3(256), 0, stream>>>(H_v, weight, HWo);
    mm_kernel<<<dim3(36, Bb, 7), dim3(256), 0, stream>>>(Tsc, Tpl, Ppart);
    reduce_kernel<<<dim3(36 * Bb, 2), dim3(256), 0, stream>>>(Ppart, adj_v, Aout);
    out_kernel<<<dim3(Nn / 8, Bb), dim3(256), 0, stream>>>(Aout, HWo, bias, out);
}

// Round 4
// 710.094 us; speedup vs baseline: 1.3216x; 1.0057x over previous
//
#include <hip/hip_runtime.h>

// Problem constants (from reference setup_inputs)
#define Bb 2
#define Nn 1024
#define Ee 8192
#define DV 64   // IN_V == OUT_V == IN_E == 64

typedef __attribute__((ext_vector_type(8))) short short8;
typedef __attribute__((ext_vector_type(8))) unsigned short ushort8;
typedef __attribute__((ext_vector_type(4))) float floatx4;

// fp32 -> bf16 bits, round-to-nearest-even
static __device__ __forceinline__ unsigned short f2bf(float f) {
    unsigned int u = __float_as_uint(f);
    unsigned int r = (u + 0x7FFFu + ((u >> 16) & 1u)) >> 16;
    return (unsigned short)r;
}
static __device__ __forceinline__ float bf2f(unsigned short u) {
    return __uint_as_float(((unsigned int)u) << 16);
}

// scale[b*E + e] = dot(H_e[row,:64], p[:64]); one wave per row
__global__ __launch_bounds__(256) void scale_kernel(const float* __restrict__ He,
                                                    const float* __restrict__ p,
                                                    float* __restrict__ scale) {
    int wave = threadIdx.x >> 6;
    int lane = threadIdx.x & 63;
    int row = blockIdx.x * 4 + wave;
    float v = He[row * 64 + lane] * p[lane];
    #pragma unroll
    for (int off = 32; off > 0; off >>= 1) v += __shfl_xor(v, off);
    if (lane == 0) scale[row] = v;
}

// Pre-cast T (fp32) -> Tsc (bf16, scaled by scale[e]) and Tpl (bf16, plain)
__global__ __launch_bounds__(256) void cast_kernel(const float* __restrict__ T,
                                                   const float* __restrict__ scale,
                                                   unsigned short* __restrict__ Tsc,
                                                   unsigned short* __restrict__ Tpl) {
    size_t i4 = (size_t)blockIdx.x * 256 + threadIdx.x;   // float4 index
    size_t e0 = i4 * 4;                                   // element index
    int b = (int)(e0 >> 23);                              // 2^23 elems per batch
    int e = (int)(e0 & 8191);                             // column within row
    floatx4 t = *(const floatx4*)&T[e0];
    floatx4 s = *(const floatx4*)&scale[(size_t)b * Ee + e];
    ushort4 sc, pl;
    sc.x = f2bf(t.x * s.x); sc.y = f2bf(t.y * s.y);
    sc.z = f2bf(t.z * s.z); sc.w = f2bf(t.w * s.w);
    pl.x = f2bf(t.x); pl.y = f2bf(t.y);
    pl.z = f2bf(t.z); pl.w = f2bf(t.w);
    *(ushort4*)&Tsc[e0] = sc;
    *(ushort4*)&Tpl[e0] = pl;
}

// HW = H_v @ weight   [B*N,64] @ [64,64]
__global__ __launch_bounds__(256) void hw_kernel(const float* __restrict__ Hv,
                                                 const float* __restrict__ W,
                                                 float* __restrict__ HWo) {
    __shared__ float Ws[64 * 64];
    __shared__ float Hvs[4 * 64];
    int t = threadIdx.x;
    for (int i = t; i < 4096; i += 256) Ws[i] = W[i];
    int r0 = blockIdx.x * 4;
    Hvs[t] = Hv[(size_t)r0 * 64 + t];
    __syncthreads();
    int d = t & 63, rr = t >> 6;
    float acc = 0.f;
    #pragma unroll
    for (int c = 0; c < 64; ++c) acc += Hvs[rr * 64 + c] * Ws[c * 64 + d];
    HWo[(size_t)(r0 + rr) * 64 + d] = acc;
}

// out[b,n,d] = bias[d]  (accumulation target for fuse_kernel atomics)
__global__ __launch_bounds__(256) void binit_kernel(const float* __restrict__ bias,
                                                    float* __restrict__ out) {
    int idx = (blockIdx.x * 256 + threadIdx.x) * 4;
    floatx4 bv = *(const floatx4*)&bias[idx & 63];
    *(floatx4*)&out[idx] = bv;
}

// Partial M1 tiles: upper-triangular 128x128 tiles, K-split 7, bf16 partial store.
// global_load_lds (16B) staging into XOR-swizzled LDS (see R3 notes).
__global__ __launch_bounds__(256, 2) void mm_kernel(const unsigned short* __restrict__ Tsc,
                                                    const unsigned short* __restrict__ Tpl,
                                                    unsigned short* __restrict__ Ppart) {
    __shared__ __attribute__((aligned(16))) unsigned short As[128 * 64];
    __shared__ __attribute__((aligned(16))) unsigned short Bs[128 * 64];
    const int t = threadIdx.x;
    const int tile = blockIdx.x;     // 0..35 upper-triangular
    const int b = blockIdx.y;
    const int s = blockIdx.z;        // 0..6 K-split

    int i = 0, rem = tile;
    while (rem >= 8 - i) { rem -= 8 - i; ++i; }
    const int j = i + rem;
    const int n0 = i * 128, m0 = j * 128;

    const int lane = t & 63;
    const int w = t >> 6;
    const int wr = w >> 1, wc = w & 1;      // 2x2 wave grid, each wave 64x64
    const int quad = lane >> 4;
    const int l15 = lane & 15;
    const int l7 = l15 & 7;

    const int lr = lane >> 3;               // row within staged 8-row group
    const int lc = (lane & 7) ^ lr;         // swizzled global chunk this lane fetches

    const int kc0 = (s * 128) / 7 * 64;
    const int kc1 = ((s + 1) * 128) / 7 * 64;

    const unsigned short* gA = Tsc + ((size_t)b * Nn + n0 + w * 32 + lr) * Ee + kc0 + lc * 8;
    const unsigned short* gB = Tpl + ((size_t)b * Nn + m0 + w * 32 + lr) * Ee + kc0 + lc * 8;
    unsigned short* lA = As + (w * 32) * 64 + lane * 8;
    unsigned short* lB = Bs + (w * 32) * 64 + lane * 8;

    floatx4 acc[4][4];
    #pragma unroll
    for (int a = 0; a < 4; ++a)
        #pragma unroll
        for (int c = 0; c < 4; ++c) acc[a][c] = (floatx4){0.f, 0.f, 0.f, 0.f};

    for (int k0 = kc0; k0 < kc1; k0 += 64) {
        #pragma unroll
        for (int u = 0; u < 4; ++u) {
            __builtin_amdgcn_global_load_lds(
                (const __attribute__((address_space(1))) unsigned int*)(gA + (size_t)u * 8 * Ee),
                (__attribute__((address_space(3))) unsigned int*)(lA + u * 8 * 64), 16, 0, 0);
            __builtin_amdgcn_global_load_lds(
                (const __attribute__((address_space(1))) unsigned int*)(gB + (size_t)u * 8 * Ee),
                (__attribute__((address_space(3))) unsigned int*)(lB + u * 8 * 64), 16, 0, 0);
        }
        gA += 64; gB += 64;
        __syncthreads();
        #pragma unroll
        for (int kk8 = 0; kk8 < 8; kk8 += 4) {
            short8 af[4], bf[4];
            #pragma unroll
            for (int a = 0; a < 4; ++a)
                af[a] = *(const short8*)&As[(wr * 64 + a * 16 + l15) * 64 + ((kk8 + quad) ^ l7) * 8];
            #pragma unroll
            for (int c = 0; c < 4; ++c)
                bf[c] = *(const short8*)&Bs[(wc * 64 + c * 16 + l15) * 64 + ((kk8 + quad) ^ l7) * 8];
            #pragma unroll
            for (int a = 0; a < 4; ++a)
                #pragma unroll
                for (int c = 0; c < 4; ++c)
                    acc[a][c] = __builtin_amdgcn_mfma_f32_16x16x32_bf16(af[a], bf[c], acc[a][c], 0, 0, 0);
        }
        __syncthreads();
    }

    unsigned short* P = Ppart + (((size_t)(b * 36 + tile)) * 7 + s) * 16384;
    #pragma unroll
    for (int a = 0; a < 4; ++a)
        #pragma unroll
        for (int c = 0; c < 4; ++c)
            #pragma unroll
            for (int v = 0; v < 4; ++v) {
                int r = wr * 64 + a * 16 + quad * 4 + v;
                int cc = wc * 64 + c * 16 + l15;
                P[r * 128 + cc] = f2bf(acc[a][c][v]);
            }
}

// Fused: sum K-split partials (bf16) for one 64x64 quadrant of an upper-tri tile,
// diag override, Hadamard both orientations (fp32), two 64x64x64 GEMMs vs HW
// (global, L2-hot), atomicAdd into bias-initialized out. Eliminates Aout.
__global__ __launch_bounds__(256) void fuse_kernel(const unsigned short* __restrict__ Ppart,
                                                   const float* __restrict__ adj_v,
                                                   const float* __restrict__ HWo,
                                                   float* __restrict__ out) {
    __shared__ float Ls[64 * 68];    // raw M1 sums (pad 68: 16B-aligned rows)
    __shared__ float Lsn[64 * 68];   // sums * adj_v[n,m]
    __shared__ float Lst[64 * 68];   // transposed sums * adj_v[m,n]
    const int t = threadIdx.x;
    const int job = blockIdx.x;      // 0..71
    const int quad = blockIdx.y;     // 0..3
    const int b = job / 36;
    const int tile = job % 36;
    int i = 0, rem = tile;
    while (rem >= 8 - i) { rem -= 8 - i; ++i; }
    const int j = i + rem;
    const int qr = quad >> 1, qc = quad & 1;
    const int n0 = i * 128 + qr * 64;   // global row base of quadrant
    const int m0 = j * 128 + qc * 64;   // global col base of quadrant
    const unsigned short* P = Ppart + (size_t)job * 7 * 16384 + (qr * 64) * 128 + qc * 64;
    const float* AV = adj_v + (size_t)b * Nn * Nn;
    const float* HW = HWo + (size_t)b * Nn * 64;

    // Phase A: sum 7 bf16 partials -> Ls; Lsn = Ls * AV[n,m] (+ diag override)
    {
        int r = t >> 2, c0 = (t & 3) * 16;
        float sv[16];
        #pragma unroll
        for (int x = 0; x < 16; ++x) sv[x] = 0.f;
        #pragma unroll
        for (int sp = 0; sp < 7; ++sp) {
            const unsigned short* ps = P + sp * 16384 + r * 128 + c0;
            ushort8 u0 = *(const ushort8*)ps;
            ushort8 u1 = *(const ushort8*)(ps + 8);
            #pragma unroll
            for (int x = 0; x < 8; ++x) {
                sv[x] += bf2f(u0[x]);
                sv[8 + x] += bf2f(u1[x]);
            }
        }
        if (i == j && qr == qc) {
            int dcol = r - c0;   // gn==gm  <=>  local r == local c
            if (dcol >= 0 && dcol < 16) sv[dcol] = 1.0f;
        }
        #pragma unroll
        for (int x4 = 0; x4 < 4; ++x4) {
            floatx4 v = (floatx4){sv[x4 * 4], sv[x4 * 4 + 1], sv[x4 * 4 + 2], sv[x4 * 4 + 3]};
            *(floatx4*)&Ls[r * 68 + c0 + x4 * 4] = v;
            floatx4 a = *(const floatx4*)&AV[(size_t)(n0 + r) * Nn + m0 + c0 + x4 * 4];
            floatx4 o = (floatx4){v.x * a.x, v.y * a.y, v.z * a.z, v.w * a.w};
            *(floatx4*)&Lsn[r * 68 + c0 + x4 * 4] = o;
        }
    }
    __syncthreads();
    // Phase B: Lst[m][r] = Ls[r][m] * AV[m0+m][n0+r]  (off-diag tiles only)
    if (i != j) {
        int m = t >> 2, r0 = (t & 3) * 16;
        #pragma unroll
        for (int x4 = 0; x4 < 4; ++x4) {
            floatx4 a = *(const floatx4*)&AV[(size_t)(m0 + m) * Nn + n0 + r0 + x4 * 4];
            floatx4 o;
            o.x = Ls[(r0 + x4 * 4 + 0) * 68 + m] * a.x;
            o.y = Ls[(r0 + x4 * 4 + 1) * 68 + m] * a.y;
            o.z = Ls[(r0 + x4 * 4 + 2) * 68 + m] * a.z;
            o.w = Ls[(r0 + x4 * 4 + 3) * 68 + m] * a.w;
            *(floatx4*)&Lst[m * 68 + r0 + x4 * 4] = o;
        }
    }
    __syncthreads();

    const int tr = t >> 4, tc = t & 15;
    // GEMM1: out[n0+4tr+ii][4tc+..] += sum_k Lsn[4tr+ii][k] * HW[m0+k][4tc+..]
    {
        floatx4 acc[4];
        #pragma unroll
        for (int ii = 0; ii < 4; ++ii) acc[ii] = (floatx4){0.f, 0.f, 0.f, 0.f};
        #pragma unroll
        for (int k4 = 0; k4 < 64; k4 += 4) {
            floatx4 bmat[4];
            #pragma unroll
            for (int u = 0; u < 4; ++u)
                bmat[u] = *(const floatx4*)&HW[(size_t)(m0 + k4 + u) * 64 + tc * 4];
            #pragma unroll
            for (int ii = 0; ii < 4; ++ii) {
                floatx4 av = *(const floatx4*)&Lsn[(tr * 4 + ii) * 68 + k4];
                acc[ii] += av.x * bmat[0];
                acc[ii] += av.y * bmat[1];
                acc[ii] += av.z * bmat[2];
                acc[ii] += av.w * bmat[3];
            }
        }
        #pragma unroll
        for (int ii = 0; ii < 4; ++ii) {
            float* op = &out[(size_t)(b * Nn + n0 + tr * 4 + ii) * 64 + tc * 4];
            atomicAdd(op + 0, acc[ii].x);
            atomicAdd(op + 1, acc[ii].y);
            atomicAdd(op + 2, acc[ii].z);
            atomicAdd(op + 3, acc[ii].w);
        }
    }
    // GEMM2 (off-diag): out[m0+4tr+ii][..] += sum_k Lst[4tr+ii][k] * HW[n0+k][..]
    if (i != j) {
        floatx4 acc[4];
        #pragma unroll
        for (int ii = 0; ii < 4; ++ii) acc[ii] = (floatx4){0.f, 0.f, 0.f, 0.f};
        #pragma unroll
        for (int k4 = 0; k4 < 64; k4 += 4) {
            floatx4 bmat[4];
            #pragma unroll
            for (int u = 0; u < 4; ++u)
                bmat[u] = *(const floatx4*)&HW[(size_t)(n0 + k4 + u) * 64 + tc * 4];
            #pragma unroll
            for (int ii = 0; ii < 4; ++ii) {
                floatx4 av = *(const floatx4*)&Lst[(tr * 4 + ii) * 68 + k4];
                acc[ii] += av.x * bmat[0];
                acc[ii] += av.y * bmat[1];
                acc[ii] += av.z * bmat[2];
                acc[ii] += av.w * bmat[3];
            }
        }
        #pragma unroll
        for (int ii = 0; ii < 4; ++ii) {
            float* op = &out[(size_t)(b * Nn + m0 + tr * 4 + ii) * 64 + tc * 4];
            atomicAdd(op + 0, acc[ii].x);
            atomicAdd(op + 1, acc[ii].y);
            atomicAdd(op + 2, acc[ii].z);
            atomicAdd(op + 3, acc[ii].w);
        }
    }
}

extern "C" void kernel_launch(void* const* d_in, const int* in_sizes, int n_in,
                              void* d_out, int out_size, void* d_ws, size_t ws_size,
                              hipStream_t stream) {
    const float* H_v    = (const float*)d_in[0];
    const float* H_e    = (const float*)d_in[1];
    // d_in[2] = adj_e : UNUSED by the reference output
    const float* adj_v  = (const float*)d_in[3];
    const float* T      = (const float*)d_in[4];
    const float* weight = (const float*)d_in[5];
    const float* p      = (const float*)d_in[6];
    const float* bias   = (const float*)d_in[7];
    float* out = (float*)d_out;

    char* ws = (char*)d_ws;
    float* scale          = (float*)ws;                                      // 64 KB
    float* HWo            = (float*)(ws + (1 << 16));                        // 512 KB
    unsigned short* Tsc   = (unsigned short*)(ws + (1 << 20));               // 32 MB
    unsigned short* Tpl   = (unsigned short*)(ws + (1 << 20) + (32u << 20)); // 32 MB
    unsigned short* Ppart = (unsigned short*)(ws + (1 << 20) + (64u << 20)); // 16.5 MB bf16

    // Output chunk 1: H_e passthrough (fp32, exact)
    hipMemcpyAsync(out + (size_t)Bb * Nn * DV, H_e,
                   (size_t)Bb * Ee * 64 * sizeof(float),
                   hipMemcpyDeviceToDevice, stream);

    binit_kernel<<<dim3((Bb * Nn * DV) / 1024), dim3(256), 0, stream>>>(bias, out);
    scale_kernel<<<dim3(Bb * Ee / 4), dim3(256), 0, stream>>>(H_e, p, scale);
    cast_kernel<<<dim3((Bb * Nn * Ee / 4) / 256), dim3(256), 0, stream>>>(T, scale, Tsc, Tpl);
    hw_kernel<<<dim3(Bb * Nn / 4), dim3(256), 0, stream>>>(H_v, weight, HWo);
    mm_kernel<<<dim3(36, Bb, 7), dim3(256), 0, stream>>>(Tsc, Tpl, Ppart);
    fuse_kernel<<<dim3(36 * Bb, 4), dim3(256), 0, stream>>>(Ppart, adj_v, HWo, out);
}